// Round 3
// baseline (269.812 us; speedup 1.0000x reference)
//
#include <hip/hip_runtime.h>
#include <cstdint>
#include <cstddef>

#define N_NODES 50000
#define N_EDGES 1600000
#define IN_FEAT 512
#define OUT_FEAT 128
#define NEG_SLOPE 0.01f
#define INV_TEMP 2.0f
#define PAD_DEG 128     // P(Poisson(32) >= 128) ~ e^-81: never

// two-phase CSR build
#define BUCKETS 400
#define BNODES 125      // nodes per bucket (400*125 = 50000)
#define BCAP 5000       // bucket capacity; Poisson(4000) max over 400 ~ 4300
#define A_BLOCKS 250
#define A_EPC (N_EDGES / A_BLOCKS)   // 6400 edges per block
#define A_G4 (A_EPC / 4)             // 1600 int4 groups

#define CONV_BLOCKS ((IN_FEAT * OUT_FEAT) / 256)   // 256
#define GEMM_BLOCKS ((N_NODES + 127) / 128)        // 391 (tile 128x128)

typedef __attribute__((ext_vector_type(8))) short short8;
typedef __attribute__((ext_vector_type(4))) float f32x4;

#define GLOBAL_AS __attribute__((address_space(1)))
#define LDS_AS __attribute__((address_space(3)))

__device__ inline unsigned short f2bf(float x) {
    unsigned int u = __float_as_uint(x);
    unsigned int r = (u + 0x7fffu + ((u >> 16) & 1u)) >> 16;
    return (unsigned short)r;
}
__device__ inline float bf2f(unsigned short b) {
    return __uint_as_float(((unsigned int)b) << 16);
}

// ---------------- K2: fused {binA, convert_w} ----------------
// Independent roles, block-partitioned. Requires bucket_cursor pre-zeroed
// (hipMemsetAsync before this kernel).

__global__ __launch_bounds__(256) void build_kernel(const float* __restrict__ W,
                                                    unsigned short* __restrict__ Wt,
                                                    const int* __restrict__ src,
                                                    const int* __restrict__ dst,
                                                    int* __restrict__ bucket_cursor,
                                                    int* __restrict__ binned) {
    __shared__ int cntL[BUCKETS];
    __shared__ int baseL[BUCKETS];

    if (blockIdx.x >= A_BLOCKS) {
        // ---- convert_w role: W (IN_FEAT x OUT_FEAT, row-major) -> Wt bf16 [n][k]
        int tid = (blockIdx.x - A_BLOCKS) * 256 + threadIdx.x;
        if (tid < IN_FEAT * OUT_FEAT) {
            int n = tid >> 9;
            int k = tid & 511;
            Wt[tid] = f2bf(W[k * OUT_FEAT + n]);
        }
        return;
    }

    // ---- binA role: bin edges by bucket (LDS-counted; one device atomic per
    // (block, non-empty bucket) to reserve global ranges).
    int t = threadIdx.x;
    for (int i = t; i < BUCKETS; i += 256) cntL[i] = 0;
    __syncthreads();
    size_t ebase = (size_t)blockIdx.x * A_EPC;

    // pass 1: count per bucket (LDS atomics)
    for (int g = t; g < A_G4; g += 256) {
        int4 s4 = *(const int4*)(src + ebase + (size_t)g * 4);
#pragma unroll
        for (int j = 0; j < 4; ++j) {
            int s = (&s4.x)[j];
            atomicAdd(&cntL[s / BNODES], 1);
        }
    }
    __syncthreads();
    // reserve global ranges
    for (int i = t; i < BUCKETS; i += 256) {
        int c = cntL[i];
        baseL[i] = c ? atomicAdd(&bucket_cursor[i], c) : 0;
        cntL[i] = 0;
    }
    __syncthreads();
    // pass 2: write packed (src_local<<16)|dst into reserved slots
    for (int g = t; g < A_G4; g += 256) {
        int4 s4 = *(const int4*)(src + ebase + (size_t)g * 4);
        int4 d4 = *(const int4*)(dst + ebase + (size_t)g * 4);
#pragma unroll
        for (int j = 0; j < 4; ++j) {
            int s = (&s4.x)[j];
            int b = s / BNODES;
            int sl = s - b * BNODES;
            int pos = atomicAdd(&cntL[b], 1);
            int slot = baseL[b] + pos;
            if (slot < BCAP)
                binned[(size_t)b * BCAP + slot] = (sl << 16) | (&d4.x)[j];
        }
    }
}

// ---------------- K3: fused {binB, mfma_gemm} ----------------
// binB blocks (0..399) scatter binned -> padded CSR; gemm blocks (400..790)
// run the MFMA GEMM.
//
// v3 GEMM: ZERO barriers, ZERO LDS in the k-loop.
//  * Round-2 counters showed 92% stall (MfmaUtil 3.6, VALU 7.3, HBM 16%):
//    the per-k-step __syncthreads drains vmcnt(0) including the h prefetch,
//    so every wave waits full HBM latency in lockstep, 8x per block.
//  * B-fragments are loaded DIRECTLY from Wt (128 KB, L2-resident): the LDS
//    slot lane L read was byte-identical to
//    Wt[(nb*16+(L&15))*512 + k0 + ksub*32 + (L>>4)*8 .. +8].
//  * Each wave owns 32 rows (m_rep=2): block tile 128x128, B-fragment reused
//    for 2 MFMAs, 32 MFMAs per wave per k-step. h read exactly once.
//  * Waves run free; fully-unrolled k-loop lets the compiler pipeline loads
//    across steps. Latency hiding by ILP + TLP, no lockstep drain.

__global__ __launch_bounds__(256) void gemm_binB_kernel(const float* __restrict__ h,
                                                        const unsigned short* __restrict__ Wt,
                                                        const float* __restrict__ a_vec,
                                                        unsigned short* __restrict__ Whb,
                                                        float* __restrict__ s1,
                                                        float* __restrict__ s2,
                                                        const int* __restrict__ bucket_cursor,
                                                        const int* __restrict__ binned,
                                                        int* __restrict__ cnt,
                                                        int* __restrict__ csr) {
    __shared__ int cL[BNODES];   // binB only; gemm role uses no LDS

    if (blockIdx.x < BUCKETS) {
        // ---- binB role: bucket -> padded CSR
        int b = blockIdx.x;
        int t = threadIdx.x;
        if (t < BNODES) cL[t] = 0;
        __syncthreads();
        int m = min(bucket_cursor[b], BCAP);
        const int* bp = binned + (size_t)b * BCAP;
        int n0 = b * BNODES;
        for (int i = t; i < m; i += 256) {
            int p = bp[i];
            int sl = p >> 16;
            int d = p & 0xFFFF;
            int pos = atomicAdd(&cL[sl], 1);
            if (pos < PAD_DEG) csr[(size_t)(n0 + sl) * PAD_DEG + pos] = d;
        }
        __syncthreads();
        if (t < BNODES) cnt[n0 + t] = min(cL[t], PAD_DEG);
        return;
    }

    // ---- gemm role
    int bid = blockIdx.x - BUCKETS;
    int t = threadIdx.x;
    int w = t >> 6;
    int L = t & 63;
    int m0 = bid * 128;
    int col0 = L & 15;
    int kq = (L >> 4) * 8;

    // wave w owns rows [m0 + w*32, +32); m-frag m covers +m*16
    int arow[2];
    bool arow_ok[2];
    const float* arp[2];
#pragma unroll
    for (int m = 0; m < 2; ++m) {
        arow[m] = m0 + w * 32 + m * 16 + col0;
        arow_ok[m] = arow[m] < N_NODES;
        arp[m] = h + (size_t)arow[m] * IN_FEAT + kq;
    }

    // per-lane B base: row (nb*16 + col0), k-slice kq
    const unsigned short* bbase = Wt + (size_t)col0 * IN_FEAT + kq;

    f32x4 acc[2][8];
#pragma unroll
    for (int m = 0; m < 2; ++m)
#pragma unroll
        for (int nb = 0; nb < 8; ++nb) acc[m][nb] = (f32x4){0.f, 0.f, 0.f, 0.f};

    // A prologue: load k-step 0
    float4 av[2][2][2];   // [m][half][quad]
#pragma unroll
    for (int m = 0; m < 2; ++m)
#pragma unroll
        for (int c = 0; c < 2; ++c) {
            av[m][c][0] = make_float4(0.f, 0.f, 0.f, 0.f);
            av[m][c][1] = make_float4(0.f, 0.f, 0.f, 0.f);
        }
#pragma unroll
    for (int m = 0; m < 2; ++m)
        if (arow_ok[m]) {
            av[m][0][0] = *(const float4*)(arp[m]);
            av[m][0][1] = *(const float4*)(arp[m] + 4);
            av[m][1][0] = *(const float4*)(arp[m] + 32);
            av[m][1][1] = *(const float4*)(arp[m] + 36);
        }

#pragma unroll
    for (int it = 0; it < 8; ++it) {
        const int k0 = it * 64;

        // issue next step's A loads first (no barrier anywhere -> they stay
        // in flight under this step's B loads + MFMAs)
        float4 avn[2][2][2];
#pragma unroll
        for (int m = 0; m < 2; ++m)
#pragma unroll
            for (int c = 0; c < 2; ++c) {
                avn[m][c][0] = make_float4(0.f, 0.f, 0.f, 0.f);
                avn[m][c][1] = make_float4(0.f, 0.f, 0.f, 0.f);
            }
        if (it < 7) {
#pragma unroll
            for (int m = 0; m < 2; ++m)
                if (arow_ok[m]) {
                    const float* p = arp[m] + (it + 1) * 64;
                    avn[m][0][0] = *(const float4*)(p);
                    avn[m][0][1] = *(const float4*)(p + 4);
                    avn[m][1][0] = *(const float4*)(p + 32);
                    avn[m][1][1] = *(const float4*)(p + 36);
                }
        }

        // B-fragments for this step: direct from L2-resident Wt
        short8 bfr[2][8];   // [ksub][nb]
#pragma unroll
        for (int ksub = 0; ksub < 2; ++ksub)
#pragma unroll
            for (int nb = 0; nb < 8; ++nb)
                bfr[ksub][nb] =
                    *(const short8*)(bbase + (size_t)nb * 16 * IN_FEAT + k0 + ksub * 32);

        // convert this step's A fragments in-register
        short8 af[2][2];   // [m][ksub]
#pragma unroll
        for (int m = 0; m < 2; ++m)
#pragma unroll
            for (int c = 0; c < 2; ++c) {
                short8 v;
                v[0] = (short)f2bf(av[m][c][0].x); v[1] = (short)f2bf(av[m][c][0].y);
                v[2] = (short)f2bf(av[m][c][0].z); v[3] = (short)f2bf(av[m][c][0].w);
                v[4] = (short)f2bf(av[m][c][1].x); v[5] = (short)f2bf(av[m][c][1].y);
                v[6] = (short)f2bf(av[m][c][1].z); v[7] = (short)f2bf(av[m][c][1].w);
                af[m][c] = v;
            }

#pragma unroll
        for (int ksub = 0; ksub < 2; ++ksub)
#pragma unroll
            for (int nb = 0; nb < 8; ++nb) {
#pragma unroll
                for (int m = 0; m < 2; ++m)
                    acc[m][nb] = __builtin_amdgcn_mfma_f32_16x16x32_bf16(af[m][ksub],
                                                                         bfr[ksub][nb],
                                                                         acc[m][nb], 0, 0, 0);
            }

#pragma unroll
        for (int m = 0; m < 2; ++m)
#pragma unroll
            for (int c = 0; c < 2; ++c) {
                av[m][c][0] = avn[m][c][0];
                av[m][c][1] = avn[m][c][1];
            }
    }

    // epilogue: store Whb (bf16) + fused s1/s2 dot products
    float a1c[8], a2c[8];
#pragma unroll
    for (int nb = 0; nb < 8; ++nb) {
        a1c[nb] = a_vec[nb * 16 + col0];
        a2c[nb] = a_vec[128 + nb * 16 + col0];
    }

#pragma unroll
    for (int m = 0; m < 2; ++m) {
        int rbase = m0 + w * 32 + m * 16 + (L >> 4) * 4;
#pragma unroll
        for (int r = 0; r < 4; ++r) {
            int row = rbase + r;
            bool ok = row < N_NODES;
            float p1 = 0.f, p2 = 0.f;
            if (ok) {
                unsigned short* orow = Whb + (size_t)row * OUT_FEAT;
#pragma unroll
                for (int nb = 0; nb < 8; ++nb) {
                    float v = acc[m][nb][r];
                    orow[nb * 16 + col0] = f2bf(v);
                    p1 = fmaf(v, a1c[nb], p1);
                    p2 = fmaf(v, a2c[nb], p2);
                }
            }
#pragma unroll
            for (int off = 8; off > 0; off >>= 1) {
                p1 += __shfl_xor(p1, off, 64);
                p2 += __shfl_xor(p2, off, 64);
            }
            if (ok && col0 == 0) {
                s1[row] = p1;
                s2[row] = p2;
            }
        }
    }
}

// ---------------- per-node softmax + aggregation ----------------
// One wave per node; lane group g = lane>>4 handles edge jj+g; lane covers
// features (lane&15)*8..+7 via one 16B short8 load -> 4 rows (1KB) per wave
// instruction. Invalid edges contribute p=0 (their source lane's ex is 0).

__global__ __launch_bounds__(256) void node_kernel(const unsigned short* __restrict__ Whb,
                                                   const float* __restrict__ s1,
                                                   const float* __restrict__ s2,
                                                   const int* __restrict__ cnt,
                                                   const int* __restrict__ csr,
                                                   float* __restrict__ out) {
    int lane = threadIdx.x & 63;
    int w = threadIdx.x >> 6;
    int n = blockIdx.x * 4 + w;
    if (n >= N_NODES) return;
    int deg = cnt[n];
    size_t start = (size_t)n * PAD_DEG;
    int g = lane >> 4;
    int fo = lane & 15;

    float accv[8];
#pragma unroll
    for (int f = 0; f < 8; ++f) accv[f] = 0.f;
    float inv = 0.f;

    if (deg > 0) {
        float s1n = s1[n];
        int d0 = 0, d1 = 0;
        float ex0 = 0.f, ex1 = 0.f;
        if (lane < deg) {
            d0 = csr[start + lane];
            float ev = s1n + s2[d0];
            ev = ev >= 0.f ? ev : NEG_SLOPE * ev;
            ex0 = __expf(ev * INV_TEMP);
        }
        if (lane + 64 < deg) {
            d1 = csr[start + lane + 64];
            float ev = s1n + s2[d1];
            ev = ev >= 0.f ? ev : NEG_SLOPE * ev;
            ex1 = __expf(ev * INV_TEMP);
        }
        float denom = ex0 + ex1;
#pragma unroll
        for (int off = 32; off > 0; off >>= 1) denom += __shfl_xor(denom, off, 64);
        inv = 1.0f / denom;

#pragma unroll 2
        for (int jj = 0; jj < deg; jj += 4) {
            int e = jj + g;
            bool hi = jj >= 64;             // wave-uniform
            float exs = hi ? ex1 : ex0;
            int dsel = hi ? d1 : d0;
            float p = __shfl(exs, e & 63, 64);
            int dd = __shfl(dsel, e & 63, 64);
            short8 row = *(const short8*)(Whb + (size_t)dd * OUT_FEAT + fo * 8);
#pragma unroll
            for (int f = 0; f < 8; ++f)
                accv[f] = fmaf(p, bf2f((unsigned short)row[f]), accv[f]);
        }
#pragma unroll
        for (int f = 0; f < 8; ++f) {
            accv[f] += __shfl_xor(accv[f], 16, 64);
            accv[f] += __shfl_xor(accv[f], 32, 64);
        }
    }

    if (g == 0) {
        float* orow = out + (size_t)n * OUT_FEAT + fo * 8;
        float4 o0, o1;
        o0.x = fmaxf(accv[0] * inv, 0.f); o0.y = fmaxf(accv[1] * inv, 0.f);
        o0.z = fmaxf(accv[2] * inv, 0.f); o0.w = fmaxf(accv[3] * inv, 0.f);
        o1.x = fmaxf(accv[4] * inv, 0.f); o1.y = fmaxf(accv[5] * inv, 0.f);
        o1.z = fmaxf(accv[6] * inv, 0.f); o1.w = fmaxf(accv[7] * inv, 0.f);
        *(float4*)(orow) = o0;
        *(float4*)(orow + 4) = o1;
    }
}

// ---------------- launch ----------------

extern "C" void kernel_launch(void* const* d_in, const int* in_sizes, int n_in,
                              void* d_out, int out_size, void* d_ws, size_t ws_size,
                              hipStream_t stream) {
    const float* h = (const float*)d_in[0];
    const float* W = (const float*)d_in[1];
    const float* a = (const float*)d_in[2];
    const int* edge = (const int*)d_in[3];
    const int* src = edge;
    const int* dst = edge + N_EDGES;
    float* out = (float*)d_out;

    char* ws = (char*)d_ws;
    size_t off = 0;
    auto alloc = [&](size_t bytes) -> void* {
        void* p = ws + off;
        off = (off + bytes + 255) & ~(size_t)255;
        return p;
    };
    unsigned short* Whb = (unsigned short*)alloc((size_t)N_NODES * OUT_FEAT * sizeof(unsigned short));
    float* s1 = (float*)alloc((size_t)N_NODES * sizeof(float));
    float* s2 = (float*)alloc((size_t)N_NODES * sizeof(float));
    int* cnt = (int*)alloc((size_t)N_NODES * sizeof(int));
    int* csr = (int*)alloc((size_t)N_NODES * PAD_DEG * sizeof(int));
    unsigned short* Wt = (unsigned short*)alloc((size_t)IN_FEAT * OUT_FEAT * sizeof(unsigned short));
    int* bucket_cursor = (int*)alloc((size_t)BUCKETS * sizeof(int));
    int* binned = (int*)alloc((size_t)BUCKETS * BCAP * sizeof(int));

    hipMemsetAsync(bucket_cursor, 0, BUCKETS * sizeof(int), stream);
    build_kernel<<<A_BLOCKS + CONV_BLOCKS, 256, 0, stream>>>(W, Wt, src, dst, bucket_cursor, binned);
    gemm_binB_kernel<<<BUCKETS + GEMM_BLOCKS, 256, 0, stream>>>(h, Wt, a, Whb, s1, s2,
                                                                bucket_cursor, binned, cnt, csr);
    node_kernel<<<(N_NODES + 3) / 4, 256, 0, stream>>>(Whb, s1, s2, cnt, csr, out);
}